// Round 6
// baseline (634.620 us; speedup 1.0000x reference)
//
#include <hip/hip_runtime.h>
#include <hip/hip_bf16.h>

typedef unsigned short ushort_t;

#define B_ 64
#define S_ 512
#define E_ 256
#define H_ 128
#define M_ (B_ * S_)   // 32768 rows
#define CAP_ 128       // max neighbor slots (nnz ~ Binom(512,0.05): mean 25.6, max ~55)

// Y scratch layout: [b][chunk=col/16][512][16]  (exchanged between the 4
// blocks of a batch inside one dispatch, via device-scope flag barrier)
// h layout: row-major [row][128]

// ---------------------------------------------------------------------------
// K1: neighbor lists from binary adj (float4 reads) + invdeg = 1/(nnz+1).
// Also zeroes the 256 barrier flags (ws is poisoned 0xAA before every call).
// ---------------------------------------------------------------------------
__global__ void k_adjidx(const float* __restrict__ adj,
                         ushort_t* __restrict__ idxl,
                         int* __restrict__ nnz,
                         float* __restrict__ invdeg,
                         int* __restrict__ flags) {
    if (blockIdx.x == 0 && threadIdx.x < 256) flags[threadIdx.x] = 0;
    int row  = blockIdx.x * 4 + (threadIdx.x >> 6);
    int lane = threadIdx.x & 63;
    const float4* arow = (const float4*)(adj + (size_t)row * S_);
    ushort_t* dst = idxl + (size_t)row * CAP_;
    int total = 0;
    #pragma unroll
    for (int c = 0; c < 2; ++c) {
        float4 v = arow[c * 64 + lane];
        float f[4] = {v.x, v.y, v.z, v.w};
        #pragma unroll
        for (int j = 0; j < 4; ++j) {
            unsigned long long m = __ballot(f[j] != 0.0f);
            if (f[j] != 0.0f) {
                int pos = total + __popcll(m & ((1ull << lane) - 1ull));
                if (pos < CAP_) dst[pos] = (ushort_t)(c * 256 + lane * 4 + j);
            }
            total += __popcll(m);
        }
    }
    if (lane == 0) {
        nnz[row] = total < CAP_ ? total : CAP_;
        invdeg[row] = 1.0f / (float)(total + 1);
    }
}

// ---------------------------------------------------------------------------
// K2: fused layer kernel. 256 blocks (4 per batch) x 512 threads (8 waves).
// Phase A (GEMM): block's 128 rows x all 128 cols: Y = X @ W^T.
//   Per wave: 16 rows. Col halves of 64; K halves of 128 (K=256 only).
//   W slab [128k][64] in LDS (block-shared, syncthreads-guarded); X streamed
//   through per-wave LDS slab (same-wave DS ordering, no barriers).
// Batch barrier: fence + atomicAdd(flag[b]) + spin to 4 + fence.
//   Safe: all 256 blocks co-resident (<= 1/CU by grid size).
// Phase B (agg): per 16-col chunk, load batch Y slab (512x16, 32 KB) to LDS,
//   gather neighbors from LDS, fused +2b, *invdeg, relu -> h row-major.
// ---------------------------------------------------------------------------
template <int K, bool GATHER>
__global__ __launch_bounds__(512) void k_layer(const float* __restrict__ Xin,
                                               const int* __restrict__ sent,
                                               const float* __restrict__ emb,
                                               const float* __restrict__ W,
                                               const float* __restrict__ bias,
                                               const ushort_t* __restrict__ idxl,
                                               const int* __restrict__ nnz,
                                               const float* __restrict__ invdeg,
                                               float* __restrict__ Y,
                                               int* __restrict__ flag,
                                               float* __restrict__ hout) {
    __shared__ __align__(16) float lds[11264];   // 45056 B
    int tid  = threadIdx.x;
    int wave = tid >> 6, lane = tid & 63;
    int b = blockIdx.x >> 2, q = blockIdx.x & 3;
    int rowBase = b * 512 + q * 128 + wave * 16;   // this wave's 16 rows

    float* Ws = lds;                          // [128][68] = 8704 floats
    float* Xs = lds + 8704 + wave * 320;      // per-wave [16][20]

    int rr = lane >> 4, cc = lane & 15;       // micro-tile: 4 rows x 4 cols
    int xrow = lane & 15, xkg = lane >> 4;    // staging: row, k-group

    const float* xbase;
    if (GATHER) xbase = emb + (size_t)sent[rowBase + xrow] * K + xkg * 4;
    else        xbase = Xin + (size_t)(rowBase + xrow) * K + xkg * 4;

    constexpr int NKH = K / 128;

    for (int ch = 0; ch < 2; ++ch) {
        float acc[4][4] = {};
        for (int kh = 0; kh < NKH; ++kh) {
            __syncthreads();                  // Ws reuse guard
            {   // load W slab: cols ch*64..+63, k kh*128..+127 (k-major)
                int j  = tid & 63;
                int k0 = (tid >> 6) * 16;
                const float* wp = W + (size_t)(ch * 64 + j) * K + kh * 128 + k0;
                #pragma unroll
                for (int i = 0; i < 4; ++i) {
                    float4 v = *(const float4*)(wp + i * 4);
                    int k = k0 + i * 4;
                    Ws[(k + 0) * 68 + j] = v.x; Ws[(k + 1) * 68 + j] = v.y;
                    Ws[(k + 2) * 68 + j] = v.z; Ws[(k + 3) * 68 + j] = v.w;
                }
            }
            __syncthreads();
            const float* xp = xbase + kh * 128;
            float4 f = *(const float4*)xp;
            #pragma unroll 1
            for (int kk = 0; kk < 128; kk += 16) {
                Xs[(xkg * 4 + 0) * 20 + xrow] = f.x;
                Xs[(xkg * 4 + 1) * 20 + xrow] = f.y;
                Xs[(xkg * 4 + 2) * 20 + xrow] = f.z;
                Xs[(xkg * 4 + 3) * 20 + xrow] = f.w;
                if (kk + 16 < 128) f = *(const float4*)(xp + kk + 16);
                #pragma unroll
                for (int k = 0; k < 16; ++k) {
                    float4 x  = *(const float4*)&Xs[k * 20 + rr * 4];
                    float4 wv = *(const float4*)&Ws[(kk + k) * 68 + cc * 4];
                    acc[0][0] += x.x * wv.x; acc[0][1] += x.x * wv.y;
                    acc[0][2] += x.x * wv.z; acc[0][3] += x.x * wv.w;
                    acc[1][0] += x.y * wv.x; acc[1][1] += x.y * wv.y;
                    acc[1][2] += x.y * wv.z; acc[1][3] += x.y * wv.w;
                    acc[2][0] += x.z * wv.x; acc[2][1] += x.z * wv.y;
                    acc[2][2] += x.z * wv.z; acc[2][3] += x.z * wv.w;
                    acc[3][0] += x.w * wv.x; acc[3][1] += x.w * wv.y;
                    acc[3][2] += x.w * wv.z; acc[3][3] += x.w * wv.w;
                }
            }
        }
        // write Y (chunked): rows rowBase+rr*4+i, cols ch*64+cc*4..+3
        int col   = ch * 64 + cc * 4;
        int chunk = col >> 4, jo = col & 15;
        #pragma unroll
        for (int i = 0; i < 4; ++i) {
            int rq = q * 128 + wave * 16 + rr * 4 + i;
            float4 o = {acc[i][0], acc[i][1], acc[i][2], acc[i][3]};
            *(float4*)(Y + (((size_t)b * 8 + chunk) * 512 + rq) * 16 + jo) = o;
        }
    }

    // ---- batch-local barrier: the 4 blocks of batch b exchange Y ----
    __threadfence();                          // publish Y (device scope)
    __syncthreads();
    if (tid == 0) {
        atomicAdd(flag + b, 1);               // device-scope by default
        while (__hip_atomic_load(flag + b, __ATOMIC_RELAXED,
                                 __HIP_MEMORY_SCOPE_AGENT) < 4)
            __builtin_amdgcn_s_sleep(2);
    }
    __syncthreads();
    __threadfence();                          // acquire: no stale lines

    // ---- phase B: aggregate + epilogue ----
    float4* s4 = (float4*)lds;                // 512x16 slab = 2048 float4
    int r   = tid >> 2;                       // 0..127 local row
    int j   = tid & 3;                        // float4 col in chunk
    int row = b * 512 + q * 128 + r;
    int rq  = q * 128 + r;
    int n = nnz[row];
    const ushort_t* il = idxl + (size_t)row * CAP_;
    float inv = invdeg[row];

    #pragma unroll 1
    for (int ch2 = 0; ch2 < 8; ++ch2) {
        __syncthreads();                      // slab reuse guard
        const float4* g4 = (const float4*)(Y + ((size_t)b * 8 + ch2) * 512 * 16);
        #pragma unroll
        for (int i = 0; i < 4; ++i) s4[tid + i * 512] = g4[tid + i * 512];
        __syncthreads();

        float4 acc = s4[rq * 4 + j];
        float4 acc2 = {0.f, 0.f, 0.f, 0.f};
        int t = 0;
        for (; t + 4 <= n; t += 4) {
            int t0 = il[t], t1 = il[t + 1], t2 = il[t + 2], t3 = il[t + 3];
            float4 v0 = s4[t0 * 4 + j];
            float4 v1 = s4[t1 * 4 + j];
            float4 v2 = s4[t2 * 4 + j];
            float4 v3 = s4[t3 * 4 + j];
            acc.x += v0.x + v1.x; acc.y += v0.y + v1.y;
            acc.z += v0.z + v1.z; acc.w += v0.w + v1.w;
            acc2.x += v2.x + v3.x; acc2.y += v2.y + v3.y;
            acc2.z += v2.z + v3.z; acc2.w += v2.w + v3.w;
        }
        for (; t < n; ++t) {
            float4 v = s4[il[t] * 4 + j];
            acc.x += v.x; acc.y += v.y; acc.z += v.z; acc.w += v.w;
        }
        acc.x += acc2.x; acc.y += acc2.y; acc.z += acc2.z; acc.w += acc2.w;

        float4 bv = *(const float4*)(bias + ch2 * 16 + j * 4);
        float4 o;
        o.x = fmaxf((acc.x + 2.0f * bv.x) * inv, 0.0f);
        o.y = fmaxf((acc.y + 2.0f * bv.y) * inv, 0.0f);
        o.z = fmaxf((acc.z + 2.0f * bv.z) * inv, 0.0f);
        o.w = fmaxf((acc.w + 2.0f * bv.w) * inv, 0.0f);
        *(float4*)(hout + (size_t)row * H_ + ch2 * 16 + j * 4) = o;
    }
}

// ---------------------------------------------------------------------------
// K3: partial max-pool: block (b,q) reduces 128 rows -> pp[b*4+q][128]
// ---------------------------------------------------------------------------
__global__ void k_pool(const float* __restrict__ h, float* __restrict__ pp) {
    int b = blockIdx.x >> 2, qq = blockIdx.x & 3, j = threadIdx.x;  // 128 thr
    const float* p = h + ((size_t)b * 512 + qq * 128) * H_ + j;
    float m = -1e30f;
    #pragma unroll 8
    for (int s = 0; s < 128; ++s) m = fmaxf(m, p[(size_t)s * H_]);
    pp[(size_t)blockIdx.x * H_ + j] = m;
}

// ---------------------------------------------------------------------------
// K4: finish pool (4 partials) + logits[b,c] = pooled . Wp[c,:] + bp[c]
// ---------------------------------------------------------------------------
__global__ void k_final(const float* __restrict__ pp,
                        const float* __restrict__ Wp,
                        const float* __restrict__ bp,
                        float* __restrict__ out) {
    int b = blockIdx.x, j = threadIdx.x;  // 128 threads
    float m = pp[(size_t)(b * 4 + 0) * H_ + j];
    m = fmaxf(m, pp[(size_t)(b * 4 + 1) * H_ + j]);
    m = fmaxf(m, pp[(size_t)(b * 4 + 2) * H_ + j]);
    m = fmaxf(m, pp[(size_t)(b * 4 + 3) * H_ + j]);
    float t0 = m * Wp[j];
    float t1 = m * Wp[H_ + j];
    #pragma unroll
    for (int off = 32; off > 0; off >>= 1) {
        t0 += __shfl_down(t0, off);
        t1 += __shfl_down(t1, off);
    }
    __shared__ float red[2][2];
    int wave = j >> 6, lane = j & 63;
    if (lane == 0) { red[0][wave] = t0; red[1][wave] = t1; }
    __syncthreads();
    if (j == 0) out[b * 2 + 0] = red[0][0] + red[0][1] + bp[0];
    if (j == 1) out[b * 2 + 1] = red[1][0] + red[1][1] + bp[1];
}

// ---------------------------------------------------------------------------
extern "C" void kernel_launch(void* const* d_in, const int* in_sizes, int n_in,
                              void* d_out, int out_size, void* d_ws, size_t ws_size,
                              hipStream_t stream) {
    const int*   sent = (const int*)d_in[0];
    const float* adj  = (const float*)d_in[1];
    const float* emb  = (const float*)d_in[2];
    const float* W1   = (const float*)d_in[3];
    const float* b1   = (const float*)d_in[4];
    const float* W2   = (const float*)d_in[5];
    const float* b2   = (const float*)d_in[6];
    const float* W3   = (const float*)d_in[7];
    const float* b3   = (const float*)d_in[8];
    const float* Wp   = (const float*)d_in[9];
    const float* bp   = (const float*)d_in[10];
    float* out = (float*)d_out;

    char* ws = (char*)d_ws;
    float* Ybuf = (float*)ws;                                   // 16 MiB
    float* h2   = (float*)(ws + ((size_t)16 << 20));            // 16 MiB
    float* h1   = (float*)(ws + ((size_t)32 << 20));            // 16 MiB
    char*  base = ws + ((size_t)48 << 20);
    float*    invdeg = (float*)base;                            // M f32
    int*      nnz    = (int*)(base + (size_t)M_ * 4);
    ushort_t* idxl   = (ushort_t*)(base + (size_t)M_ * 8);      // M*CAP u16 = 8 MiB
    float*    pp     = (float*)(base + (size_t)M_ * 8 + (size_t)M_ * CAP_ * 2);  // 256*128 f32
    int*      flags  = (int*)(base + (size_t)M_ * 8 + (size_t)M_ * CAP_ * 2 + 256 * H_ * 4);  // 256 ints

    k_adjidx<<<M_ / 4, 256, 0, stream>>>(adj, idxl, nnz, invdeg, flags);

    k_layer<E_, true ><<<256, 512, 0, stream>>>(nullptr, sent, emb, W1, b1,
                                                idxl, nnz, invdeg, Ybuf, flags + 0,   h1);
    k_layer<H_, false><<<256, 512, 0, stream>>>(h1, nullptr, nullptr, W2, b2,
                                                idxl, nnz, invdeg, Ybuf, flags + 64,  h2);
    k_layer<H_, false><<<256, 512, 0, stream>>>(h2, nullptr, nullptr, W3, b3,
                                                idxl, nnz, invdeg, Ybuf, flags + 128, h1);

    k_pool <<<256, H_, 0, stream>>>(h1, pp);
    k_final<<<B_,  H_, 0, stream>>>(pp, Wp, bp, out);
}

// Round 7
// 433.035 us; speedup vs baseline: 1.4655x; 1.4655x over previous
//
#include <hip/hip_runtime.h>
#include <hip/hip_bf16.h>

typedef unsigned short ushort_t;

#define B_ 64
#define S_ 512
#define E_ 256
#define H_ 128
#define M_ (B_ * S_)   // 32768 rows
#define CAP_ 128       // max neighbor slots (nnz ~ Binom(512,0.05): mean 25.6, max ~55)

// ---------------------------------------------------------------------------
// K1: neighbor lists from binary adj (float4 reads) + invdeg = 1/(nnz+1)
// ---------------------------------------------------------------------------
__global__ void k_adjidx(const float* __restrict__ adj,
                         ushort_t* __restrict__ idxl,
                         int* __restrict__ nnz,
                         float* __restrict__ invdeg) {
    int row  = blockIdx.x * 4 + (threadIdx.x >> 6);
    int lane = threadIdx.x & 63;
    const float4* arow = (const float4*)(adj + (size_t)row * S_);
    ushort_t* dst = idxl + (size_t)row * CAP_;
    int total = 0;
    #pragma unroll
    for (int c = 0; c < 2; ++c) {
        float4 v = arow[c * 64 + lane];
        float f[4] = {v.x, v.y, v.z, v.w};
        #pragma unroll
        for (int j = 0; j < 4; ++j) {
            unsigned long long m = __ballot(f[j] != 0.0f);
            if (f[j] != 0.0f) {
                int pos = total + __popcll(m & ((1ull << lane) - 1ull));
                if (pos < CAP_) dst[pos] = (ushort_t)(c * 256 + lane * 4 + j);
            }
            total += __popcll(m);
        }
    }
    if (lane == 0) {
        nnz[row] = total < CAP_ ? total : CAP_;
        invdeg[row] = 1.0f / (float)(total + 1);
    }
}

// ---------------------------------------------------------------------------
// K2: fused layer. One block = one (batch b, 16-col chunk ch). 256 threads.
// Phase A: Y[0..511][0..15] = X[batch rows][:] @ W[ch*16..+15][:]^T into LDS
//   (Y never touches global). Thread owns 4 rows x 8 cols; W slab in LDS,
//   read as wave-uniform b128 broadcasts (conflict-free); X float4-streamed
//   from global with one-step prefetch.
// Phase B: agg from the padded LDS slab (stride 20 kills pow2 bank aliasing):
//   h[row] = relu((Y[row] + sum_nbr Y[t] + 2b) * invdeg[row]), or POOL:
//   in-block max over all 512 rows -> pooled[b][ch*16..+15].
// XCD swizzle: a batch's 8 chunks share one XCD (L2 reuse of X / h writes).
// ---------------------------------------------------------------------------
template <int K, bool GATHER, bool POOL>
__global__ __launch_bounds__(256) void k_layer(const float* __restrict__ Xin,
                                               const int* __restrict__ sent,
                                               const float* __restrict__ emb,
                                               const float* __restrict__ W,
                                               const float* __restrict__ bias,
                                               const ushort_t* __restrict__ idxl,
                                               const int* __restrict__ nnz,
                                               const float* __restrict__ invdeg,
                                               float* __restrict__ out) {
    __shared__ float Ws[K * 20];       // [k][16 cols + pad4]
    __shared__ float Ys[512 * 20];     // [row][16 cols + pad4]
    int tid = threadIdx.x;
    int xcd = blockIdx.x & 7, slot = blockIdx.x >> 3;
    int b   = xcd + 8 * (slot >> 3);   // batch: fixed XCD per batch
    int ch  = slot & 7;                // 16-col chunk 0..7

    // ---- W slab load: Ws[k][j] = W[ch*16+j][k] ----
    {
        constexpr int FL = K / 16;     // floats per (col, kq)
        int j  = tid & 15;
        int kq = tid >> 4;             // 0..15
        const float* wp = W + (size_t)(ch * 16 + j) * K + kq * FL;
        #pragma unroll
        for (int i = 0; i < FL / 4; ++i) {
            float4 v = *(const float4*)(wp + i * 4);
            int k = kq * FL + i * 4;
            Ws[(k + 0) * 20 + j] = v.x; Ws[(k + 1) * 20 + j] = v.y;
            Ws[(k + 2) * 20 + j] = v.z; Ws[(k + 3) * 20 + j] = v.w;
        }
    }

    // ---- phase A: GEMM ----
    int q  = tid & 127;                // row within group of 128
    int c0 = (tid >> 7) * 8;           // col half: 0 or 8
    const float* xp[4];
    #pragma unroll
    for (int i = 0; i < 4; ++i) {
        int row = b * S_ + q + i * 128;
        if (GATHER) xp[i] = emb + (size_t)sent[row] * K;
        else        xp[i] = Xin + (size_t)row * K;
    }

    __syncthreads();                   // Ws ready

    float acc[4][8] = {};
    float4 cur[4], nxt[4];
    #pragma unroll
    for (int i = 0; i < 4; ++i) cur[i] = *(const float4*)(xp[i]);

    #pragma unroll 2
    for (int kb = 0; kb < K; kb += 4) {
        if (kb + 4 < K) {
            #pragma unroll
            for (int i = 0; i < 4; ++i) nxt[i] = *(const float4*)(xp[i] + kb + 4);
        }
        #pragma unroll
        for (int e = 0; e < 4; ++e) {
            float4 w0 = *(const float4*)&Ws[(kb + e) * 20 + c0];
            float4 w1 = *(const float4*)&Ws[(kb + e) * 20 + c0 + 4];
            float xs[4] = {((const float*)&cur[0])[e], ((const float*)&cur[1])[e],
                           ((const float*)&cur[2])[e], ((const float*)&cur[3])[e]};
            #pragma unroll
            for (int i = 0; i < 4; ++i) {
                acc[i][0] += xs[i] * w0.x; acc[i][1] += xs[i] * w0.y;
                acc[i][2] += xs[i] * w0.z; acc[i][3] += xs[i] * w0.w;
                acc[i][4] += xs[i] * w1.x; acc[i][5] += xs[i] * w1.y;
                acc[i][6] += xs[i] * w1.z; acc[i][7] += xs[i] * w1.w;
            }
        }
        #pragma unroll
        for (int i = 0; i < 4; ++i) cur[i] = nxt[i];
    }

    #pragma unroll
    for (int i = 0; i < 4; ++i) {
        int r = q + i * 128;
        *(float4*)&Ys[r * 20 + c0]     = *(float4*)&acc[i][0];
        *(float4*)&Ys[r * 20 + c0 + 4] = *(float4*)&acc[i][4];
    }
    __syncthreads();                   // Ys complete

    // ---- phase B: aggregate + epilogue (rows tid and tid+256) ----
    float4 bv[4];
    #pragma unroll
    for (int j = 0; j < 4; ++j) {
        bv[j] = *(const float4*)(bias + ch * 16 + j * 4);
        bv[j].x *= 2.0f; bv[j].y *= 2.0f; bv[j].z *= 2.0f; bv[j].w *= 2.0f;
    }
    float4 vmax[4];
    #pragma unroll
    for (int j = 0; j < 4; ++j) vmax[j] = make_float4(-1e30f, -1e30f, -1e30f, -1e30f);

    #pragma unroll
    for (int p = 0; p < 2; ++p) {
        int r   = tid + p * 256;
        int row = b * S_ + r;
        int n = nnz[row];
        const ushort_t* il = idxl + (size_t)row * CAP_;
        float inv = invdeg[row];
        float4 a[4];
        #pragma unroll
        for (int j = 0; j < 4; ++j) a[j] = *(const float4*)&Ys[r * 20 + j * 4];
        for (int t = 0; t < n; ++t) {
            int tr = il[t];
            #pragma unroll
            for (int j = 0; j < 4; ++j) {
                float4 v = *(const float4*)&Ys[tr * 20 + j * 4];
                a[j].x += v.x; a[j].y += v.y; a[j].z += v.z; a[j].w += v.w;
            }
        }
        #pragma unroll
        for (int j = 0; j < 4; ++j) {
            float4 o;
            o.x = fmaxf((a[j].x + bv[j].x) * inv, 0.0f);
            o.y = fmaxf((a[j].y + bv[j].y) * inv, 0.0f);
            o.z = fmaxf((a[j].z + bv[j].z) * inv, 0.0f);
            o.w = fmaxf((a[j].w + bv[j].w) * inv, 0.0f);
            if (!POOL) {
                *(float4*)(out + (size_t)row * H_ + ch * 16 + j * 4) = o;
            } else {
                vmax[j].x = fmaxf(vmax[j].x, o.x); vmax[j].y = fmaxf(vmax[j].y, o.y);
                vmax[j].z = fmaxf(vmax[j].z, o.z); vmax[j].w = fmaxf(vmax[j].w, o.w);
            }
        }
    }

    if (POOL) {
        __syncthreads();               // all gathers done; slab reusable
        #pragma unroll
        for (int j = 0; j < 4; ++j) *(float4*)&Ys[tid * 20 + j * 4] = vmax[j];
        __syncthreads();
        if (tid < 64) {                // stage 1: 4 groups x 16 cols
            int c = tid & 15, g = tid >> 4;
            float m = -1e30f;
            #pragma unroll 8
            for (int i = 0; i < 64; ++i) m = fmaxf(m, Ys[(g * 64 + i) * 20 + c]);
            Ys[(264 + g) * 20 + c] = m;
        }
        __syncthreads();
        if (tid < 16) {                // stage 2
            float m = Ys[264 * 20 + tid];
            m = fmaxf(m, Ys[265 * 20 + tid]);
            m = fmaxf(m, Ys[266 * 20 + tid]);
            m = fmaxf(m, Ys[267 * 20 + tid]);
            out[(size_t)b * H_ + ch * 16 + tid] = m;
        }
    }
}

// ---------------------------------------------------------------------------
// K3: logits[b,c] = pooled[b,:] . Wp[c,:] + bp[c]   (pooled is [64][128])
// ---------------------------------------------------------------------------
__global__ void k_final(const float* __restrict__ pooled,
                        const float* __restrict__ Wp,
                        const float* __restrict__ bp,
                        float* __restrict__ out) {
    int b = blockIdx.x, j = threadIdx.x;  // 128 threads
    float m = pooled[(size_t)b * H_ + j];
    float t0 = m * Wp[j];
    float t1 = m * Wp[H_ + j];
    #pragma unroll
    for (int off = 32; off > 0; off >>= 1) {
        t0 += __shfl_down(t0, off);
        t1 += __shfl_down(t1, off);
    }
    __shared__ float red[2][2];
    int wave = j >> 6, lane = j & 63;
    if (lane == 0) { red[0][wave] = t0; red[1][wave] = t1; }
    __syncthreads();
    if (j == 0) out[b * 2 + 0] = red[0][0] + red[0][1] + bp[0];
    if (j == 1) out[b * 2 + 1] = red[1][0] + red[1][1] + bp[1];
}

// ---------------------------------------------------------------------------
extern "C" void kernel_launch(void* const* d_in, const int* in_sizes, int n_in,
                              void* d_out, int out_size, void* d_ws, size_t ws_size,
                              hipStream_t stream) {
    const int*   sent = (const int*)d_in[0];
    const float* adj  = (const float*)d_in[1];
    const float* emb  = (const float*)d_in[2];
    const float* W1   = (const float*)d_in[3];
    const float* b1   = (const float*)d_in[4];
    const float* W2   = (const float*)d_in[5];
    const float* b2   = (const float*)d_in[6];
    const float* W3   = (const float*)d_in[7];
    const float* b3   = (const float*)d_in[8];
    const float* Wp   = (const float*)d_in[9];
    const float* bp   = (const float*)d_in[10];
    float* out = (float*)d_out;

    char* ws = (char*)d_ws;
    float*    h1     = (float*)ws;                              // M*128 f32 = 16 MiB
    float*    h2     = (float*)(ws + ((size_t)16 << 20));       // M*128 f32 = 16 MiB
    char*     base   = ws + ((size_t)32 << 20);
    float*    invdeg = (float*)base;                            // M f32
    int*      nnz    = (int*)(base + (size_t)M_ * 4);
    ushort_t* idxl   = (ushort_t*)(base + (size_t)M_ * 8);      // M*CAP u16 = 8 MiB
    float*    pooled = (float*)(base + (size_t)M_ * 8 + (size_t)M_ * CAP_ * 2);  // 64*128 f32

    k_adjidx<<<M_ / 4, 256, 0, stream>>>(adj, idxl, nnz, invdeg);

    k_layer<E_, true,  false><<<512, 256, 0, stream>>>(nullptr, sent, emb, W1, b1,
                                                       idxl, nnz, invdeg, h1);
    k_layer<H_, false, false><<<512, 256, 0, stream>>>(h1, nullptr, nullptr, W2, b2,
                                                       idxl, nnz, invdeg, h2);
    k_layer<H_, false, true ><<<512, 256, 0, stream>>>(h2, nullptr, nullptr, W3, b3,
                                                       idxl, nnz, invdeg, pooled);

    k_final<<<B_, H_, 0, stream>>>(pooled, Wp, bp, out);
}